// Round 2
// baseline (151.589 us; speedup 1.0000x reference)
//
#include <hip/hip_runtime.h>

typedef float f4 __attribute__((ext_vector_type(4)));

// v_t_d / v_l_d row gather: [vmain(384) | v1(64) | v2(32) | v0(64)] along tokens
__device__ __forceinline__ float gather_vd(const float* vmain, const float* v0, const float* v1,
                                           const float* v2, int b, int t, int d) {
    const float* p; int r;
    if (t < 384)      { p = vmain; r = b * 384 + t;        }
    else if (t < 448) { p = v1;    r = b * 64  + (t - 384); }
    else if (t < 480) { p = v2;    r = b * 32  + (t - 448); }
    else              { p = v0;    r = b * 64  + (t - 480); }
    return p[r * 128 + d];
}

// K1: attT[side][b][d][t] = bias[d] + sum_k v_row[k] * W[d][k]   (transposed store for K2)
__global__ __launch_bounds__(128) void k_att(const float* v0, const float* v1, const float* v2,
                                             const float* vt, const float* vl,
                                             const float* Wt, const float* bt,
                                             const float* Wl, const float* bl,
                                             float* attT) {
    int t = blockIdx.x, b = blockIdx.y, side = blockIdx.z;
    int d = threadIdx.x;
    __shared__ float in_lds[128];
    const float* vmain = side ? vl : vt;
    in_lds[d] = gather_vd(vmain, v0, v1, v2, b, t, d);
    __syncthreads();
    const float* W    = side ? Wl : Wt;
    const float* bias = side ? bl : bt;
    float acc = bias[d];
    const f4* wrow = (const f4*)(W + d * 128);
    #pragma unroll
    for (int kc = 0; kc < 32; ++kc) {
        f4 wv = wrow[kc];
        #pragma unroll
        for (int j = 0; j < 4; ++j) acc += in_lds[kc * 4 + j] * wv[j];
    }
    attT[((size_t)(side * 2 + b) * 128 + d) * 544 + t] = acc;
}

// K2: S[so][b][t][d];  so=0: mean over l of lrelu(tA+lA); so=1: mean over t.
// lrelu(x) = 0.505x + 0.495|x|  =>  sum_l lrelu(c+o[l]) = 0.505*(544c + sum_o) + 0.495*sum|c+o[l]|
__global__ __launch_bounds__(256) void k_pair(const float* attT, float* S) {
    int d = blockIdx.x, b = blockIdx.y, so = blockIdx.z;
    int tid = threadIdx.x;
    __shared__ float trow[544], lrow[544], red[4];
    for (int i = tid; i < 544; i += 256) {
        trow[i] = attT[((size_t)(0 * 2 + b) * 128 + d) * 544 + i];
        lrow[i] = attT[((size_t)(1 * 2 + b) * 128 + d) * 544 + i];
    }
    __syncthreads();
    const float* selfr  = so ? lrow : trow;
    const float* otherr = so ? trow : lrow;
    float p = 0.f;
    for (int i = tid; i < 544; i += 256) p += otherr[i];
    #pragma unroll
    for (int off = 32; off > 0; off >>= 1) p += __shfl_down(p, off, 64);
    int lane = tid & 63, wid = tid >> 6;
    if (lane == 0) red[wid] = p;
    __syncthreads();
    float sum_o = red[0] + red[1] + red[2] + red[3];
    for (int t = tid; t < 544; t += 256) {
        float c = selfr[t];
        float s = 0.f;
        #pragma unroll 4
        for (int l = 0; l < 544; ++l) s += fabsf(c + otherr[l]);
        float res = (0.505f * (544.f * c + sum_o) + 0.495f * s) * (1.0f / 544.f);
        S[((size_t)(so * 2 + b) * 544 + t) * 128 + d] = res;
    }
}

// K3: atte = sigmoid(S @ Wa^T + ba) -> f32 outputs 1/2; fused gating atomicAdd into x[b][256]
__global__ __launch_bounds__(128) void k_atte(const float* S, const float* Wa, const float* ba,
                                              const float* v0, const float* v1, const float* v2,
                                              const float* vt, const float* vl,
                                              float* out, float* x) {
    int t = blockIdx.x, b = blockIdx.y, side = blockIdx.z;
    int d = threadIdx.x;
    __shared__ float s_lds[128];
    s_lds[d] = S[((size_t)(side * 2 + b) * 544 + t) * 128 + d];
    __syncthreads();
    float acc = ba[d];
    const f4* wrow = (const f4*)(Wa + d * 128);
    #pragma unroll
    for (int kc = 0; kc < 32; ++kc) {
        f4 wv = wrow[kc];
        #pragma unroll
        for (int j = 0; j < 4; ++j) acc += s_lds[kc * 4 + j] * wv[j];
    }
    float atte = 1.f / (1.f + expf(-acc));
    out[4 + side * 139264 + ((size_t)b * 544 + t) * 128 + d] = atte;
    const float* vmain = side ? vl : vt;
    float vval = gather_vd(vmain, v0, v1, v2, b, t, d);
    atomicAdd(&x[b * 256 + side * 128 + d], vval * (0.5f + atte));
}

// FC layer: thread-per-output GEMV, input row staged in LDS, float4 weight loads
template <int K, int OUT_TOTAL, bool LRELU>
__global__ __launch_bounds__(256) void k_fc(const float* in, const float* W, const float* bias,
                                            float* outv) {
    int gid = blockIdx.x * 256 + threadIdx.x;
    const int opb = OUT_TOTAL / 2;
    int b = gid / opb, o = gid % opb;
    __shared__ float in_lds[K];
    for (int i = threadIdx.x; i < K; i += 256) in_lds[i] = in[b * K + i];
    __syncthreads();
    float acc = bias[o];
    const f4* wrow = (const f4*)(W + (size_t)o * K);
    #pragma unroll 4
    for (int kc = 0; kc < K / 4; ++kc) {
        f4 wv = wrow[kc];
        #pragma unroll
        for (int j = 0; j < 4; ++j) acc += in_lds[kc * 4 + j] * wv[j];
    }
    if (LRELU) acc = acc > 0.f ? acc : 0.01f * acc;
    outv[gid] = acc;
}

// K7: predict[b][o] = f3[b,:] . Wo[o,:] + bo[o]  (4 outputs, one wave each)
__global__ __launch_bounds__(256) void k_pred(const float* f3, const float* Wo, const float* bo,
                                              float* out) {
    int tid = threadIdx.x;
    int idx = tid >> 6, lane = tid & 63;
    int b = idx >> 1, o = idx & 1;
    float acc = 0.f;
    #pragma unroll
    for (int k = lane; k < 256; k += 64) acc += f3[b * 256 + k] * Wo[o * 256 + k];
    #pragma unroll
    for (int off = 32; off > 0; off >>= 1) acc += __shfl_down(acc, off, 64);
    if (lane == 0) out[b * 2 + o] = acc + bo[o];
}

extern "C" void kernel_launch(void* const* d_in, const int* in_sizes, int n_in,
                              void* d_out, int out_size, void* d_ws, size_t ws_size,
                              hipStream_t stream) {
    (void)in_sizes; (void)n_in; (void)out_size; (void)ws_size;
    const float* v0 = (const float*)d_in[0];
    const float* v1 = (const float*)d_in[1];
    const float* v2 = (const float*)d_in[2];
    const float* vt = (const float*)d_in[3];
    const float* vl = (const float*)d_in[4];
    const float* Wt = (const float*)d_in[5];
    const float* bt = (const float*)d_in[6];
    const float* Wl = (const float*)d_in[7];
    const float* bl = (const float*)d_in[8];
    const float* Wa = (const float*)d_in[9];
    const float* ba = (const float*)d_in[10];
    const float* W1 = (const float*)d_in[11];
    const float* b1 = (const float*)d_in[12];
    const float* W2 = (const float*)d_in[13];
    const float* b2 = (const float*)d_in[14];
    const float* W3 = (const float*)d_in[15];
    const float* b3 = (const float*)d_in[16];
    const float* Wo = (const float*)d_in[17];
    const float* bo = (const float*)d_in[18];

    float* ws   = (float*)d_ws;
    float* attT = ws;                 // [2][2][128][544] = 278528
    float* S    = ws + 278528;        // [2][2][544][128] = 278528
    float* x    = ws + 557056;        // [2][256]
    float* f1v  = ws + 557568;        // [2][1024]
    float* f2v  = ws + 559616;        // [2][512]
    float* f3v  = ws + 560640;        // [2][256]
    float* out = (float*)d_out;

    hipMemsetAsync(x, 0, 512 * sizeof(float), stream);
    k_att<<<dim3(544, 2, 2), 128, 0, stream>>>(v0, v1, v2, vt, vl, Wt, bt, Wl, bl, attT);
    k_pair<<<dim3(128, 2, 2), 256, 0, stream>>>(attT, S);
    k_atte<<<dim3(544, 2, 2), 128, 0, stream>>>(S, Wa, ba, v0, v1, v2, vt, vl, out, x);
    k_fc<256, 2048, true><<<8, 256, 0, stream>>>(x, W1, b1, f1v);
    k_fc<1024, 1024, true><<<4, 256, 0, stream>>>(f1v, W2, b2, f2v);
    k_fc<512, 512, true><<<2, 256, 0, stream>>>(f2v, W3, b3, f3v);
    k_pred<<<1, 256, 0, stream>>>(f3v, Wo, bo, out);
}

// Round 3
// 94.161 us; speedup vs baseline: 1.6099x; 1.6099x over previous
//
#include <hip/hip_runtime.h>

typedef float f4 __attribute__((ext_vector_type(4)));

// Uniform (per-block) row pointer into concatenated v_t_d / v_l_d:
// [vmain(384) | v1(64) | v2(32) | v0(64)] along tokens
__device__ __forceinline__ const float* vd_row(const float* vmain, const float* v0,
                                               const float* v1, const float* v2,
                                               int b, int t) {
    if (t < 384)      return vmain + ((size_t)b * 384 + t) * 128;
    else if (t < 448) return v1    + ((size_t)b * 64 + (t - 384)) * 128;
    else if (t < 480) return v2    + ((size_t)b * 32 + (t - 448)) * 128;
    else              return v0    + ((size_t)b * 64 + (t - 480)) * 128;
}

// K1: attT[side][b][d][t] = bias[d] + sum_k row[k] * W[d][k]  (transposed store for K2)
// row[] is wave-uniform -> scalar loads; no LDS, no barrier.
__global__ __launch_bounds__(128) void k_att(const float* __restrict__ v0, const float* __restrict__ v1,
                                             const float* __restrict__ v2, const float* __restrict__ vt,
                                             const float* __restrict__ vl,
                                             const float* __restrict__ Wt, const float* __restrict__ bt,
                                             const float* __restrict__ Wl, const float* __restrict__ bl,
                                             float* __restrict__ attT) {
    int t = blockIdx.x, b = blockIdx.y, side = blockIdx.z;
    int d = threadIdx.x;
    const float* row  = vd_row(side ? vl : vt, v0, v1, v2, b, t);
    const float* W    = side ? Wl : Wt;
    const float* bias = side ? bl : bt;
    float acc = bias[d];
    const f4* wrow = (const f4*)(W + d * 128);
    #pragma unroll
    for (int kc = 0; kc < 32; ++kc) {
        f4 wv = wrow[kc];
        #pragma unroll
        for (int j = 0; j < 4; ++j) acc += row[kc * 4 + j] * wv[j];
    }
    attT[((size_t)(side * 2 + b) * 128 + d) * 544 + t] = acc;
}

// K2: S[so][b][t][d]; so=0: mean over l of lrelu(tA+lA); so=1: mean over t.
// lrelu(x) = 0.505x + 0.495|x| => sum_l lrelu(c+o[l]) = 0.505*(544c + sum_o) + 0.495*sum|c+o[l]|
// otherr[] is wave-uniform -> scalar loads feed VALU; 2 VALU / element floor.
__global__ __launch_bounds__(256) void k_pair(const float* __restrict__ attT, float* __restrict__ S) {
    int d = blockIdx.x, b = blockIdx.y, so = blockIdx.z;
    int tid = threadIdx.x;
    const float* trow = attT + ((size_t)(0 * 2 + b) * 128 + d) * 544;
    const float* lrow = attT + ((size_t)(1 * 2 + b) * 128 + d) * 544;
    const float* selfr  = so ? lrow : trow;
    const float* otherr = so ? trow : lrow;
    __shared__ float red[4];
    float p = 0.f;
    for (int i = tid; i < 544; i += 256) p += otherr[i];
    #pragma unroll
    for (int off = 32; off > 0; off >>= 1) p += __shfl_down(p, off, 64);
    int lane = tid & 63, wid = tid >> 6;
    if (lane == 0) red[wid] = p;
    __syncthreads();
    float sum_o = red[0] + red[1] + red[2] + red[3];
    for (int t = tid; t < 544; t += 256) {
        float c = selfr[t];
        float s = 0.f;
        #pragma unroll 8
        for (int l = 0; l < 544; ++l) s += fabsf(c + otherr[l]);
        float res = (0.505f * (544.f * c + sum_o) + 0.495f * s) * (1.0f / 544.f);
        S[((size_t)(so * 2 + b) * 544 + t) * 128 + d] = res;
    }
}

// K3: atte = sigmoid(S @ Wa^T + ba) -> outputs 1/2; fused gating atomicAdd into x[b][256].
// srow[] is wave-uniform -> scalar loads; no LDS, no barrier.
__global__ __launch_bounds__(128) void k_atte(const float* __restrict__ S, const float* __restrict__ Wa,
                                              const float* __restrict__ ba,
                                              const float* __restrict__ v0, const float* __restrict__ v1,
                                              const float* __restrict__ v2, const float* __restrict__ vt,
                                              const float* __restrict__ vl,
                                              float* __restrict__ out, float* __restrict__ x) {
    int t = blockIdx.x, b = blockIdx.y, side = blockIdx.z;
    int d = threadIdx.x;
    const float* srow = S + ((size_t)(side * 2 + b) * 544 + t) * 128;
    float acc = ba[d];
    const f4* wrow = (const f4*)(Wa + d * 128);
    #pragma unroll
    for (int kc = 0; kc < 32; ++kc) {
        f4 wv = wrow[kc];
        #pragma unroll
        for (int j = 0; j < 4; ++j) acc += srow[kc * 4 + j] * wv[j];
    }
    float atte = 1.f / (1.f + expf(-acc));
    out[4 + side * 139264 + ((size_t)b * 544 + t) * 128 + d] = atte;
    const float* vrow = vd_row(side ? vl : vt, v0, v1, v2, b, t);
    atomicAdd(&x[b * 256 + side * 128 + d], vrow[d] * (0.5f + atte));
}

// FC layer: one wave per output element, K split across 64 lanes (f4 each), butterfly reduce.
template <int K, int OUT_TOTAL, bool LRELU>
__global__ __launch_bounds__(256) void k_fc(const float* __restrict__ in, const float* __restrict__ W,
                                            const float* __restrict__ bias, float* __restrict__ outv) {
    int wave = blockIdx.x * 4 + (threadIdx.x >> 6);
    int lane = threadIdx.x & 63;
    const int opb = OUT_TOTAL / 2;
    int b = wave / opb, o = wave % opb;
    const f4* wrow = (const f4*)(W + (size_t)o * K);
    const f4* inr  = (const f4*)(in + (size_t)b * K);
    float acc = 0.f;
    #pragma unroll
    for (int c = 0; c < K / 256; ++c) {
        f4 wv = wrow[c * 64 + lane];
        f4 iv = inr[c * 64 + lane];
        acc += wv[0] * iv[0] + wv[1] * iv[1] + wv[2] * iv[2] + wv[3] * iv[3];
    }
    #pragma unroll
    for (int off = 32; off > 0; off >>= 1) acc += __shfl_down(acc, off, 64);
    if (lane == 0) {
        acc += bias[o];
        if (LRELU) acc = acc > 0.f ? acc : 0.01f * acc;
        outv[wave] = acc;
    }
}

// K7: predict[b][o] = f3[b,:] . Wo[o,:] + bo[o]  (4 outputs, one wave each)
__global__ __launch_bounds__(256) void k_pred(const float* __restrict__ f3, const float* __restrict__ Wo,
                                              const float* __restrict__ bo, float* __restrict__ out) {
    int tid = threadIdx.x;
    int idx = tid >> 6, lane = tid & 63;
    int b = idx >> 1, o = idx & 1;
    float acc = 0.f;
    #pragma unroll
    for (int k = lane; k < 256; k += 64) acc += f3[b * 256 + k] * Wo[o * 256 + k];
    #pragma unroll
    for (int off = 32; off > 0; off >>= 1) acc += __shfl_down(acc, off, 64);
    if (lane == 0) out[b * 2 + o] = acc + bo[o];
}

extern "C" void kernel_launch(void* const* d_in, const int* in_sizes, int n_in,
                              void* d_out, int out_size, void* d_ws, size_t ws_size,
                              hipStream_t stream) {
    (void)in_sizes; (void)n_in; (void)out_size; (void)ws_size;
    const float* v0 = (const float*)d_in[0];
    const float* v1 = (const float*)d_in[1];
    const float* v2 = (const float*)d_in[2];
    const float* vt = (const float*)d_in[3];
    const float* vl = (const float*)d_in[4];
    const float* Wt = (const float*)d_in[5];
    const float* bt = (const float*)d_in[6];
    const float* Wl = (const float*)d_in[7];
    const float* bl = (const float*)d_in[8];
    const float* Wa = (const float*)d_in[9];
    const float* ba = (const float*)d_in[10];
    const float* W1 = (const float*)d_in[11];
    const float* b1 = (const float*)d_in[12];
    const float* W2 = (const float*)d_in[13];
    const float* b2 = (const float*)d_in[14];
    const float* W3 = (const float*)d_in[15];
    const float* b3 = (const float*)d_in[16];
    const float* Wo = (const float*)d_in[17];
    const float* bo = (const float*)d_in[18];

    float* ws   = (float*)d_ws;
    float* attT = ws;                 // [2][2][128][544] = 278528
    float* S    = ws + 278528;        // [2][2][544][128] = 278528
    float* x    = ws + 557056;        // [2][256]
    float* f1v  = ws + 557568;        // [2][1024]
    float* f2v  = ws + 559616;        // [2][512]
    float* f3v  = ws + 560640;        // [2][256]
    float* out = (float*)d_out;

    hipMemsetAsync(x, 0, 512 * sizeof(float), stream);
    k_att<<<dim3(544, 2, 2), 128, 0, stream>>>(v0, v1, v2, vt, vl, Wt, bt, Wl, bl, attT);
    k_pair<<<dim3(128, 2, 2), 256, 0, stream>>>(attT, S);
    k_atte<<<dim3(544, 2, 2), 128, 0, stream>>>(S, Wa, ba, v0, v1, v2, vt, vl, out, x);
    k_fc<256, 2048, true><<<512, 256, 0, stream>>>(x, W1, b1, f1v);
    k_fc<1024, 1024, true><<<256, 256, 0, stream>>>(f1v, W2, b2, f2v);
    k_fc<512, 512, true><<<128, 256, 0, stream>>>(f2v, W3, b3, f3v);
    k_pred<<<1, 256, 0, stream>>>(f3v, Wo, bo, out);
}